// Round 1
// baseline (1891.921 us; speedup 1.0000x reference)
//
#include <hip/hip_runtime.h>
#include <math.h>

#define V 2048
#define C 64
#define NB 8

// ---------------- Kernel 1: adj[n,i,j] = exp(-0.5 * ||x[n,i]-x[n,j]||) ----------------
// 64x64 tile per block, 256 threads, 4x4 micro-tile per thread.
__global__ __launch_bounds__(256) void adj_kernel(const float* __restrict__ x,
                                                  float* __restrict__ adj) {
    const int n  = blockIdx.z;
    const int i0 = blockIdx.y * 64;
    const int j0 = blockIdx.x * 64;

    __shared__ float Xi[64][65];
    __shared__ float Xj[64][65];

    const float* xn = x + (size_t)n * V * C;
    const int tid = threadIdx.x;

    // Stage 64x64 x-tiles (rows i0.., j0..), float4 loads.
    const int lr = tid >> 4;          // 0..15
    const int lc = (tid & 15) << 2;   // 0..60
#pragma unroll
    for (int it = 0; it < 4; ++it) {
        const int r = lr + it * 16;
        float4 vi = *(const float4*)(xn + (size_t)(i0 + r) * C + lc);
        float4 vj = *(const float4*)(xn + (size_t)(j0 + r) * C + lc);
        Xi[r][lc + 0] = vi.x; Xi[r][lc + 1] = vi.y; Xi[r][lc + 2] = vi.z; Xi[r][lc + 3] = vi.w;
        Xj[r][lc + 0] = vj.x; Xj[r][lc + 1] = vj.y; Xj[r][lc + 2] = vj.z; Xj[r][lc + 3] = vj.w;
    }
    __syncthreads();

    const int ti = (tid >> 4) << 2;   // row offset within tile
    const int tj = (tid & 15) << 2;   // col offset within tile

    float acc[4][4] = {};
#pragma unroll 4
    for (int c = 0; c < C; ++c) {
        float ai[4], bj[4];
#pragma unroll
        for (int a = 0; a < 4; ++a) ai[a] = Xi[ti + a][c];
#pragma unroll
        for (int b = 0; b < 4; ++b) bj[b] = Xj[tj + b][c];
#pragma unroll
        for (int a = 0; a < 4; ++a)
#pragma unroll
            for (int b = 0; b < 4; ++b) {
                const float d = ai[a] - bj[b];
                acc[a][b] = fmaf(d, d, acc[a][b]);
            }
    }

    float* outb = adj + ((size_t)n * V + i0) * V + j0;
#pragma unroll
    for (int a = 0; a < 4; ++a) {
        float4 o0, o1;
        o0.x = expf(-0.5f * sqrtf(acc[a][0]));
        o0.y = expf(-0.5f * sqrtf(acc[a][1]));
        o0.z = expf(-0.5f * sqrtf(acc[a][2]));
        o0.w = expf(-0.5f * sqrtf(acc[a][3]));
        (void)o1;
        *(float4*)(outb + (size_t)(ti + a) * V + tj) = o0;
    }
}

// ---------------- Kernel 2: in-place row-block GEMM: rows <- rows @ W ----------------
// Each block owns 8 full rows (staged in 64 KB LDS), computes all 2048 output
// columns, then overwrites its own rows. Row-local => in-place is safe.
__global__ __launch_bounds__(256) void gemm_inplace(float* __restrict__ adjout,
                                                    const float* __restrict__ w) {
    const int n  = blockIdx.y;
    const int i0 = blockIdx.x * 8;

    __shared__ float rows[8][V];   // 64 KB

    float* base = adjout + ((size_t)n * V + i0) * V;
    const int tid = threadIdx.x;

    // Stage 8 rows: 8*2048 = 16384 floats = 4096 float4, 16 per thread.
    for (int t = tid; t < (8 * V) / 4; t += 256) {
        const int r = t >> 9;             // 512 float4 per row
        const int c = (t & 511) << 2;
        float4 v = *(const float4*)(base + (size_t)r * V + c);
        rows[r][c + 0] = v.x; rows[r][c + 1] = v.y; rows[r][c + 2] = v.z; rows[r][c + 3] = v.w;
    }
    __syncthreads();

    float acc[8][8] = {};
    const int k0 = tid << 3;              // 8 output columns per thread
    const float* wp = w + k0;

    for (int j = 0; j < V; ++j) {
        float a[8];
#pragma unroll
        for (int r = 0; r < 8; ++r) a[r] = rows[r][j];   // LDS broadcast
        const float* wr = wp + (size_t)j * V;
        const float4 w0 = *(const float4*)(wr);
        const float4 w1 = *(const float4*)(wr + 4);
        const float wv[8] = {w0.x, w0.y, w0.z, w0.w, w1.x, w1.y, w1.z, w1.w};
#pragma unroll
        for (int r = 0; r < 8; ++r)
#pragma unroll
            for (int c = 0; c < 8; ++c)
                acc[r][c] = fmaf(a[r], wv[c], acc[r][c]);
    }

#pragma unroll
    for (int r = 0; r < 8; ++r) {
        float4 o0, o1;
        o0.x = acc[r][0]; o0.y = acc[r][1]; o0.z = acc[r][2]; o0.w = acc[r][3];
        o1.x = acc[r][4]; o1.y = acc[r][5]; o1.z = acc[r][6]; o1.w = acc[r][7];
        *(float4*)(base + (size_t)r * V + k0)     = o0;
        *(float4*)(base + (size_t)r * V + k0 + 4) = o1;
    }
}

// ---------------- Kernel 3: in-place row softmax ----------------
// 4 rows per block, one wave (64 lanes) per row, 32 elems per lane.
__global__ __launch_bounds__(256) void softmax_kernel(float* __restrict__ out) {
    const int row  = blockIdx.x * 4 + (threadIdx.x >> 6);
    const int lane = threadIdx.x & 63;
    float* p = out + (size_t)row * V;

    float4 v[8];
#pragma unroll
    for (int s = 0; s < 8; ++s)
        v[s] = *(const float4*)(p + (size_t)(s * 64 + lane) * 4);

    float m = -INFINITY;
#pragma unroll
    for (int s = 0; s < 8; ++s) {
        m = fmaxf(m, fmaxf(fmaxf(v[s].x, v[s].y), fmaxf(v[s].z, v[s].w)));
    }
#pragma unroll
    for (int o = 32; o; o >>= 1) m = fmaxf(m, __shfl_xor(m, o));

    float sum = 0.0f;
#pragma unroll
    for (int s = 0; s < 8; ++s) {
        v[s].x = expf(v[s].x - m);
        v[s].y = expf(v[s].y - m);
        v[s].z = expf(v[s].z - m);
        v[s].w = expf(v[s].w - m);
        sum += (v[s].x + v[s].y) + (v[s].z + v[s].w);
    }
#pragma unroll
    for (int o = 32; o; o >>= 1) sum += __shfl_xor(sum, o);

    const float inv = 1.0f / sum;
#pragma unroll
    for (int s = 0; s < 8; ++s) {
        float4 o4;
        o4.x = v[s].x * inv; o4.y = v[s].y * inv;
        o4.z = v[s].z * inv; o4.w = v[s].w * inv;
        *(float4*)(p + (size_t)(s * 64 + lane) * 4) = o4;
    }
}

extern "C" void kernel_launch(void* const* d_in, const int* in_sizes, int n_in,
                              void* d_out, int out_size, void* d_ws, size_t ws_size,
                              hipStream_t stream) {
    const float* x = (const float*)d_in[0];
    const float* w = (const float*)d_in[1];
    float* out = (float*)d_out;

    dim3 g1(V / 64, V / 64, NB);
    adj_kernel<<<g1, 256, 0, stream>>>(x, out);

    dim3 g2(V / 8, NB);
    gemm_inplace<<<g2, 256, 0, stream>>>(out, w);

    softmax_kernel<<<(NB * V) / 4, 256, 0, stream>>>(out);
}

// Round 2
// 328.303 us; speedup vs baseline: 5.7627x; 5.7627x over previous
//
#include <hip/hip_runtime.h>
#include <hip/hip_bf16.h>
#include <math.h>

#define V 2048
#define C 64
#define NB 8
#define M_TOTAL (NB * V)   // 16384 rows total

typedef __attribute__((ext_vector_type(8))) short bf16x8;
typedef __attribute__((ext_vector_type(4))) float f32x4;

static __device__ __forceinline__ unsigned short f2bf(float f) {
    __hip_bfloat16 h = __float2bfloat16(f);   // RNE
    return *reinterpret_cast<unsigned short*>(&h);
}

#define GLOAD_LDS16(g, l)                                                        \
    __builtin_amdgcn_global_load_lds((const __attribute__((address_space(1))) void*)(g), \
                                     (__attribute__((address_space(3))) void*)(l), 16, 0, 0)

// ============================ FAST PATH (needs d_ws) ============================

// ---- adj in bf16: adjb[n*V+i][j] = bf16(exp(-0.5*||x[n,i]-x[n,j]||)) ----
__global__ __launch_bounds__(256) void adj_kernel_bf16(const float* __restrict__ x,
                                                       unsigned short* __restrict__ adjb) {
    const int n  = blockIdx.z;
    const int i0 = blockIdx.y * 64;
    const int j0 = blockIdx.x * 64;

    __shared__ float Xi[64][65];
    __shared__ float Xj[64][65];

    const float* xn = x + (size_t)n * V * C;
    const int tid = threadIdx.x;
    const int lr = tid >> 4;
    const int lc = (tid & 15) << 2;
#pragma unroll
    for (int it = 0; it < 4; ++it) {
        const int r = lr + it * 16;
        float4 vi = *(const float4*)(xn + (size_t)(i0 + r) * C + lc);
        float4 vj = *(const float4*)(xn + (size_t)(j0 + r) * C + lc);
        Xi[r][lc + 0] = vi.x; Xi[r][lc + 1] = vi.y; Xi[r][lc + 2] = vi.z; Xi[r][lc + 3] = vi.w;
        Xj[r][lc + 0] = vj.x; Xj[r][lc + 1] = vj.y; Xj[r][lc + 2] = vj.z; Xj[r][lc + 3] = vj.w;
    }
    __syncthreads();

    const int ti = (tid >> 4) << 2;
    const int tj = (tid & 15) << 2;

    float acc[4][4] = {};
#pragma unroll 4
    for (int c = 0; c < C; ++c) {
        float ai[4], bj[4];
#pragma unroll
        for (int a = 0; a < 4; ++a) ai[a] = Xi[ti + a][c];
#pragma unroll
        for (int b = 0; b < 4; ++b) bj[b] = Xj[tj + b][c];
#pragma unroll
        for (int a = 0; a < 4; ++a)
#pragma unroll
            for (int b = 0; b < 4; ++b) {
                const float d = ai[a] - bj[b];
                acc[a][b] = fmaf(d, d, acc[a][b]);
            }
    }

    unsigned short* outb = adjb + ((size_t)n * V + i0) * V + j0;
#pragma unroll
    for (int a = 0; a < 4; ++a) {
        ushort4 o;
        o.x = f2bf(expf(-0.5f * sqrtf(acc[a][0])));
        o.y = f2bf(expf(-0.5f * sqrtf(acc[a][1])));
        o.z = f2bf(expf(-0.5f * sqrtf(acc[a][2])));
        o.w = f2bf(expf(-0.5f * sqrtf(acc[a][3])));
        *(ushort4*)(outb + (size_t)(ti + a) * V + tj) = o;
    }
}

// ---- W transpose to bf16: wt[c][r] = bf16(W[r][c]) ----
__global__ __launch_bounds__(256) void wt_kernel(const float* __restrict__ w,
                                                 unsigned short* __restrict__ wt) {
    __shared__ float tile[64][65];
    const int r0 = blockIdx.y * 64, c0 = blockIdx.x * 64;
    const int tr = threadIdx.x >> 4;
    const int tc4 = (threadIdx.x & 15) << 2;
#pragma unroll
    for (int it = 0; it < 4; ++it) {
        const int r = tr + 16 * it;
        float4 v = *(const float4*)(w + (size_t)(r0 + r) * V + c0 + tc4);
        tile[r][tc4 + 0] = v.x; tile[r][tc4 + 1] = v.y;
        tile[r][tc4 + 2] = v.z; tile[r][tc4 + 3] = v.w;
    }
    __syncthreads();
#pragma unroll
    for (int it = 0; it < 4; ++it) {
        const int cr = tr + 16 * it;   // WT row (= W col) within tile
        ushort4 o;
        o.x = f2bf(tile[tc4 + 0][cr]);
        o.y = f2bf(tile[tc4 + 1][cr]);
        o.z = f2bf(tile[tc4 + 2][cr]);
        o.w = f2bf(tile[tc4 + 3][cr]);
        *(ushort4*)(wt + (size_t)(c0 + cr) * V + r0 + tc4) = o;
    }
}

// ---- MFMA GEMM: out[M=16384, N=2048] = adjb @ W  (B supplied transposed: wt[N][K]) ----
// 128x128 tile, BK=32, 4 waves (2x2 of 64x64), 16x16x32 bf16 MFMA, m97-style
// global_load_lds width-16 staging, single-buffered 2-barrier K loop.
__global__ __launch_bounds__(256) void gemm_mfma(const unsigned short* __restrict__ adjb,
                                                 const unsigned short* __restrict__ wtb,
                                                 float* __restrict__ out) {
    const int bx = blockIdx.x;           // N tile: 0..15
    const int by = blockIdx.y;           // M tile: 0..127
    const int i0 = by * 128;
    const int n0 = bx * 128;

    __shared__ alignas(16) unsigned short As[128 * 32];  // [row][k] bf16
    __shared__ alignas(16) unsigned short Bs[128 * 32];  // [col][k] bf16 (= WT rows)

    const int tid  = threadIdx.x;
    const int wid  = tid >> 6;
    const int lane = tid & 63;
    const int wr = wid >> 1, wc = wid & 1;
    const int lr = lane & 15, lq = lane >> 4;

    f32x4 acc[4][4];
#pragma unroll
    for (int m = 0; m < 4; ++m)
#pragma unroll
        for (int n = 0; n < 4; ++n) acc[m][n] = (f32x4){0.f, 0.f, 0.f, 0.f};

    // staging: idx = q*256 + tid covers (row = idx>>2, colgroup = idx&3), 8 bf16 each
    const unsigned short* ga = adjb + (size_t)(i0 + (tid >> 2)) * V + (tid & 3) * 8;
    const unsigned short* gb = wtb  + (size_t)(n0 + (tid >> 2)) * V + (tid & 3) * 8;
    unsigned short* lA = &As[tid * 8];
    unsigned short* lB = &Bs[tid * 8];
    const size_t rowskip = (size_t)64 * V;   // +64 rows for second stage issue

    for (int kt = 0; kt < 64; ++kt) {
        const int k0 = kt * 32;
        if (kt) __syncthreads();           // previous compute done before overwrite
        GLOAD_LDS16(ga + k0,           lA);
        GLOAD_LDS16(ga + rowskip + k0, lA + 256 * 8);
        GLOAD_LDS16(gb + k0,           lB);
        GLOAD_LDS16(gb + rowskip + k0, lB + 256 * 8);
        __syncthreads();                    // drains vmcnt(0) + barrier

        bf16x8 a[4], b[4];
#pragma unroll
        for (int m = 0; m < 4; ++m)
            a[m] = *(const bf16x8*)&As[(wr * 64 + m * 16 + lr) * 32 + lq * 8];
#pragma unroll
        for (int n = 0; n < 4; ++n)
            b[n] = *(const bf16x8*)&Bs[(wc * 64 + n * 16 + lr) * 32 + lq * 8];
#pragma unroll
        for (int m = 0; m < 4; ++m)
#pragma unroll
            for (int n = 0; n < 4; ++n)
                acc[m][n] = __builtin_amdgcn_mfma_f32_16x16x32_bf16(a[m], b[n], acc[m][n], 0, 0, 0);
    }

    // C write: row = (lane>>4)*4 + reg, col = lane&15 within each 16x16 frag
    float* outp = out + (size_t)(i0 + wr * 64) * V + n0 + wc * 64;
#pragma unroll
    for (int m = 0; m < 4; ++m) {
        const int r0 = m * 16 + lq * 4;
#pragma unroll
        for (int n = 0; n < 4; ++n) {
            const int cc = n * 16 + lr;
#pragma unroll
            for (int r = 0; r < 4; ++r)
                outp[(size_t)(r0 + r) * V + cc] = acc[m][n][r];
        }
    }
}

// ============================ FALLBACK PATH (fp32, no ws) ============================

__global__ __launch_bounds__(256) void adj_kernel(const float* __restrict__ x,
                                                  float* __restrict__ adj) {
    const int n  = blockIdx.z;
    const int i0 = blockIdx.y * 64;
    const int j0 = blockIdx.x * 64;

    __shared__ float Xi[64][65];
    __shared__ float Xj[64][65];

    const float* xn = x + (size_t)n * V * C;
    const int tid = threadIdx.x;
    const int lr = tid >> 4;
    const int lc = (tid & 15) << 2;
#pragma unroll
    for (int it = 0; it < 4; ++it) {
        const int r = lr + it * 16;
        float4 vi = *(const float4*)(xn + (size_t)(i0 + r) * C + lc);
        float4 vj = *(const float4*)(xn + (size_t)(j0 + r) * C + lc);
        Xi[r][lc + 0] = vi.x; Xi[r][lc + 1] = vi.y; Xi[r][lc + 2] = vi.z; Xi[r][lc + 3] = vi.w;
        Xj[r][lc + 0] = vj.x; Xj[r][lc + 1] = vj.y; Xj[r][lc + 2] = vj.z; Xj[r][lc + 3] = vj.w;
    }
    __syncthreads();

    const int ti = (tid >> 4) << 2;
    const int tj = (tid & 15) << 2;

    float acc[4][4] = {};
#pragma unroll 4
    for (int c = 0; c < C; ++c) {
        float ai[4], bj[4];
#pragma unroll
        for (int a = 0; a < 4; ++a) ai[a] = Xi[ti + a][c];
#pragma unroll
        for (int b = 0; b < 4; ++b) bj[b] = Xj[tj + b][c];
#pragma unroll
        for (int a = 0; a < 4; ++a)
#pragma unroll
            for (int b = 0; b < 4; ++b) {
                const float d = ai[a] - bj[b];
                acc[a][b] = fmaf(d, d, acc[a][b]);
            }
    }

    float* outb = adj + ((size_t)n * V + i0) * V + j0;
#pragma unroll
    for (int a = 0; a < 4; ++a) {
        float4 o0;
        o0.x = expf(-0.5f * sqrtf(acc[a][0]));
        o0.y = expf(-0.5f * sqrtf(acc[a][1]));
        o0.z = expf(-0.5f * sqrtf(acc[a][2]));
        o0.w = expf(-0.5f * sqrtf(acc[a][3]));
        *(float4*)(outb + (size_t)(ti + a) * V + tj) = o0;
    }
}

__global__ __launch_bounds__(256) void gemm_inplace(float* __restrict__ adjout,
                                                    const float* __restrict__ w) {
    const int n  = blockIdx.y;
    const int i0 = blockIdx.x * 8;

    __shared__ float rows[8][V];

    float* base = adjout + ((size_t)n * V + i0) * V;
    const int tid = threadIdx.x;

    for (int t = tid; t < (8 * V) / 4; t += 256) {
        const int r = t >> 9;
        const int c = (t & 511) << 2;
        float4 v = *(const float4*)(base + (size_t)r * V + c);
        rows[r][c + 0] = v.x; rows[r][c + 1] = v.y; rows[r][c + 2] = v.z; rows[r][c + 3] = v.w;
    }
    __syncthreads();

    float acc[8][8] = {};
    const int k0 = tid << 3;
    const float* wp = w + k0;

    for (int j = 0; j < V; ++j) {
        float a[8];
#pragma unroll
        for (int r = 0; r < 8; ++r) a[r] = rows[r][j];
        const float* wr = wp + (size_t)j * V;
        const float4 w0 = *(const float4*)(wr);
        const float4 w1 = *(const float4*)(wr + 4);
        const float wv[8] = {w0.x, w0.y, w0.z, w0.w, w1.x, w1.y, w1.z, w1.w};
#pragma unroll
        for (int r = 0; r < 8; ++r)
#pragma unroll
            for (int c = 0; c < 8; ++c)
                acc[r][c] = fmaf(a[r], wv[c], acc[r][c]);
    }

#pragma unroll
    for (int r = 0; r < 8; ++r) {
        float4 o0, o1;
        o0.x = acc[r][0]; o0.y = acc[r][1]; o0.z = acc[r][2]; o0.w = acc[r][3];
        o1.x = acc[r][4]; o1.y = acc[r][5]; o1.z = acc[r][6]; o1.w = acc[r][7];
        *(float4*)(base + (size_t)r * V + k0)     = o0;
        *(float4*)(base + (size_t)r * V + k0 + 4) = o1;
    }
}

// ---------------- in-place row softmax (shared by both paths) ----------------
__global__ __launch_bounds__(256) void softmax_kernel(float* __restrict__ out) {
    const int row  = blockIdx.x * 4 + (threadIdx.x >> 6);
    const int lane = threadIdx.x & 63;
    float* p = out + (size_t)row * V;

    float4 v[8];
#pragma unroll
    for (int s = 0; s < 8; ++s)
        v[s] = *(const float4*)(p + (size_t)(s * 64 + lane) * 4);

    float m = -INFINITY;
#pragma unroll
    for (int s = 0; s < 8; ++s)
        m = fmaxf(m, fmaxf(fmaxf(v[s].x, v[s].y), fmaxf(v[s].z, v[s].w)));
#pragma unroll
    for (int o = 32; o; o >>= 1) m = fmaxf(m, __shfl_xor(m, o));

    float sum = 0.0f;
#pragma unroll
    for (int s = 0; s < 8; ++s) {
        v[s].x = expf(v[s].x - m);
        v[s].y = expf(v[s].y - m);
        v[s].z = expf(v[s].z - m);
        v[s].w = expf(v[s].w - m);
        sum += (v[s].x + v[s].y) + (v[s].z + v[s].w);
    }
#pragma unroll
    for (int o = 32; o; o >>= 1) sum += __shfl_xor(sum, o);

    const float inv = 1.0f / sum;
#pragma unroll
    for (int s = 0; s < 8; ++s) {
        float4 o4;
        o4.x = v[s].x * inv; o4.y = v[s].y * inv;
        o4.z = v[s].z * inv; o4.w = v[s].w * inv;
        *(float4*)(p + (size_t)(s * 64 + lane) * 4) = o4;
    }
}

extern "C" void kernel_launch(void* const* d_in, const int* in_sizes, int n_in,
                              void* d_out, int out_size, void* d_ws, size_t ws_size,
                              hipStream_t stream) {
    const float* x = (const float*)d_in[0];
    const float* w = (const float*)d_in[1];
    float* out = (float*)d_out;

    const size_t adj_elems = (size_t)M_TOTAL * V;                   // 33.5M bf16
    const size_t need = adj_elems * 2 + (size_t)V * V * 2;          // 75,497,472 B

    if (ws_size >= need) {
        unsigned short* adjb = (unsigned short*)d_ws;
        unsigned short* wtb  = adjb + adj_elems;

        dim3 g1(V / 64, V / 64, NB);
        adj_kernel_bf16<<<g1, 256, 0, stream>>>(x, adjb);
        wt_kernel<<<dim3(V / 64, V / 64), 256, 0, stream>>>(w, wtb);
        gemm_mfma<<<dim3(16, 128), 256, 0, stream>>>(adjb, wtb, out);
        softmax_kernel<<<(NB * V) / 4, 256, 0, stream>>>(out);
    } else {
        dim3 g1(V / 64, V / 64, NB);
        adj_kernel<<<g1, 256, 0, stream>>>(x, out);
        dim3 g2(V / 8, NB);
        gemm_inplace<<<g2, 256, 0, stream>>>(out, w);
        softmax_kernel<<<(NB * V) / 4, 256, 0, stream>>>(out);
    }
}

// Round 3
// 243.772 us; speedup vs baseline: 7.7610x; 1.3468x over previous
//
#include <hip/hip_runtime.h>
#include <hip/hip_bf16.h>
#include <math.h>

#define V 2048
#define C 64
#define NB 8
#define M_TOTAL (NB * V)   // 16384 rows total

typedef __attribute__((ext_vector_type(8))) short bf16x8;
typedef __attribute__((ext_vector_type(4))) float f32x4;

static __device__ __forceinline__ unsigned short f2bf(float f) {
    __hip_bfloat16 h = __float2bfloat16(f);   // RNE
    return *reinterpret_cast<unsigned short*>(&h);
}

#define GLOAD_LDS16(g, l)                                                        \
    __builtin_amdgcn_global_load_lds((const __attribute__((address_space(1))) void*)(g), \
                                     (__attribute__((address_space(3))) void*)(l), 16, 0, 0)

// ============================ FAST PATH (needs d_ws) ============================

// ---- q_kernel: q[row] = MFMA-diagonal of bf16(x_row) . bf16(x_row) ----
// CRITICAL: uses the exact same MFMA instruction + K-chain order + fragment
// k-mapping as adj_mfma, so q[i] bit-equals G_ii there => diagonal d^2 == 0.
__global__ __launch_bounds__(256) void q_kernel(const float* __restrict__ x,
                                                float* __restrict__ q) {
    const int gw   = blockIdx.x * 4 + (threadIdx.x >> 6);  // global wave id, 16 rows each
    const int lane = threadIdx.x & 63;
    const int lr = lane & 15, lq = lane >> 4;

    const float* rp = x + (size_t)(gw * 16 + lr) * C + lq * 8;
    float4 f0 = *(const float4*)(rp);
    float4 f1 = *(const float4*)(rp + 4);
    float4 f2 = *(const float4*)(rp + 32);
    float4 f3 = *(const float4*)(rp + 36);

    bf16x8 a0, a1;
    a0[0] = (short)f2bf(f0.x); a0[1] = (short)f2bf(f0.y);
    a0[2] = (short)f2bf(f0.z); a0[3] = (short)f2bf(f0.w);
    a0[4] = (short)f2bf(f1.x); a0[5] = (short)f2bf(f1.y);
    a0[6] = (short)f2bf(f1.z); a0[7] = (short)f2bf(f1.w);
    a1[0] = (short)f2bf(f2.x); a1[1] = (short)f2bf(f2.y);
    a1[2] = (short)f2bf(f2.z); a1[3] = (short)f2bf(f2.w);
    a1[4] = (short)f2bf(f3.x); a1[5] = (short)f2bf(f3.y);
    a1[6] = (short)f2bf(f3.z); a1[7] = (short)f2bf(f3.w);

    f32x4 acc = (f32x4){0.f, 0.f, 0.f, 0.f};
    acc = __builtin_amdgcn_mfma_f32_16x16x32_bf16(a0, a0, acc, 0, 0, 0);
    acc = __builtin_amdgcn_mfma_f32_16x16x32_bf16(a1, a1, acc, 0, 0, 0);

    // D layout: col=lane&15, row=(lane>>4)*4+reg. Diagonal (r,r): lane = ((r>>2)<<4)|r.
    const int r = lr;
    if (lq == (r >> 2)) q[gw * 16 + r] = acc[r & 3];
}

// ---- adj via MFMA gram: adjb[n*V+i][j] = bf16(exp(-0.5*sqrt(q_i+q_j-2*G_ij))) ----
// 128x128 tile per block, 4 waves (2x2 of 64x64), 16x16x32 bf16 MFMA.
__global__ __launch_bounds__(256) void adj_mfma(const float* __restrict__ x,
                                                const float* __restrict__ q,
                                                unsigned short* __restrict__ adjb) {
    const int n  = blockIdx.z;
    const int i0 = blockIdx.y * 128;
    const int j0 = blockIdx.x * 128;
    const size_t nV = (size_t)n * V;

    __shared__ short Xi[128][72];   // bf16, +8 pad (stride 144B = 9*16B)
    __shared__ short Xj[128][72];
    __shared__ float Qi[128];
    __shared__ float Qj[128];

    const float* xn = x + nV * C;
    const int tid = threadIdx.x;

    // Stage x tiles as bf16 (convert once), 1024 row-colgroups, 4 iters/thread.
    for (int idx = tid; idx < 1024; idx += 256) {
        const int row = idx >> 3;
        const int c8  = (idx & 7) * 8;
        float4 ai0 = *(const float4*)(xn + (size_t)(i0 + row) * C + c8);
        float4 ai1 = *(const float4*)(xn + (size_t)(i0 + row) * C + c8 + 4);
        float4 aj0 = *(const float4*)(xn + (size_t)(j0 + row) * C + c8);
        float4 aj1 = *(const float4*)(xn + (size_t)(j0 + row) * C + c8 + 4);
        bf16x8 pi, pj;
        pi[0] = (short)f2bf(ai0.x); pi[1] = (short)f2bf(ai0.y);
        pi[2] = (short)f2bf(ai0.z); pi[3] = (short)f2bf(ai0.w);
        pi[4] = (short)f2bf(ai1.x); pi[5] = (short)f2bf(ai1.y);
        pi[6] = (short)f2bf(ai1.z); pi[7] = (short)f2bf(ai1.w);
        pj[0] = (short)f2bf(aj0.x); pj[1] = (short)f2bf(aj0.y);
        pj[2] = (short)f2bf(aj0.z); pj[3] = (short)f2bf(aj0.w);
        pj[4] = (short)f2bf(aj1.x); pj[5] = (short)f2bf(aj1.y);
        pj[6] = (short)f2bf(aj1.z); pj[7] = (short)f2bf(aj1.w);
        *(bf16x8*)&Xi[row][c8] = pi;
        *(bf16x8*)&Xj[row][c8] = pj;
    }
    if (tid < 128)       Qi[tid]        = q[nV + i0 + tid];
    else                 Qj[tid - 128]  = q[nV + j0 + (tid - 128)];
    __syncthreads();

    const int wid  = tid >> 6;
    const int lane = tid & 63;
    const int wr = wid >> 1, wc = wid & 1;
    const int lr = lane & 15, lq = lane >> 4;

    bf16x8 a[4][2], b[4][2];
#pragma unroll
    for (int m = 0; m < 4; ++m) {
        a[m][0] = *(const bf16x8*)&Xi[wr * 64 + m * 16 + lr][lq * 8];
        a[m][1] = *(const bf16x8*)&Xi[wr * 64 + m * 16 + lr][32 + lq * 8];
    }
#pragma unroll
    for (int nn = 0; nn < 4; ++nn) {
        b[nn][0] = *(const bf16x8*)&Xj[wc * 64 + nn * 16 + lr][lq * 8];
        b[nn][1] = *(const bf16x8*)&Xj[wc * 64 + nn * 16 + lr][32 + lq * 8];
    }

#pragma unroll
    for (int m = 0; m < 4; ++m) {
#pragma unroll
        for (int nn = 0; nn < 4; ++nn) {
            f32x4 g = (f32x4){0.f, 0.f, 0.f, 0.f};
            g = __builtin_amdgcn_mfma_f32_16x16x32_bf16(a[m][0], b[nn][0], g, 0, 0, 0);
            g = __builtin_amdgcn_mfma_f32_16x16x32_bf16(a[m][1], b[nn][1], g, 0, 0, 0);
            const int col_l = wc * 64 + nn * 16 + lr;
            const float qj = Qj[col_l];
#pragma unroll
            for (int r = 0; r < 4; ++r) {
                const int row_l = wr * 64 + m * 16 + lq * 4 + r;
                float d2 = Qi[row_l] + qj - 2.0f * g[r];
                d2 = fmaxf(d2, 0.0f);
                const float e = expf(-0.5f * sqrtf(d2));
                adjb[(nV + i0 + row_l) * V + j0 + col_l] = f2bf(e);
            }
        }
    }
}

// ---- W transpose to bf16: wt[c][r] = bf16(W[r][c]) ----
__global__ __launch_bounds__(256) void wt_kernel(const float* __restrict__ w,
                                                 unsigned short* __restrict__ wt) {
    __shared__ float tile[64][65];
    const int r0 = blockIdx.y * 64, c0 = blockIdx.x * 64;
    const int tr = threadIdx.x >> 4;
    const int tc4 = (threadIdx.x & 15) << 2;
#pragma unroll
    for (int it = 0; it < 4; ++it) {
        const int r = tr + 16 * it;
        float4 v = *(const float4*)(w + (size_t)(r0 + r) * V + c0 + tc4);
        tile[r][tc4 + 0] = v.x; tile[r][tc4 + 1] = v.y;
        tile[r][tc4 + 2] = v.z; tile[r][tc4 + 3] = v.w;
    }
    __syncthreads();
#pragma unroll
    for (int it = 0; it < 4; ++it) {
        const int cr = tr + 16 * it;   // WT row (= W col) within tile
        ushort4 o;
        o.x = f2bf(tile[tc4 + 0][cr]);
        o.y = f2bf(tile[tc4 + 1][cr]);
        o.z = f2bf(tile[tc4 + 2][cr]);
        o.w = f2bf(tile[tc4 + 3][cr]);
        *(ushort4*)(wt + (size_t)(c0 + cr) * V + r0 + tc4) = o;
    }
}

// ---- MFMA GEMM: out[16384, 2048] = adjb @ W (B transposed: wt[N][K]) ----
// 128x128 tile, BK=32, 4 waves, m97-style global_load_lds staging.
// 1-D grid + bijective XCD swizzle (T1): same-M-panel blocks share an XCD's L2.
__global__ __launch_bounds__(256) void gemm_mfma(const unsigned short* __restrict__ adjb,
                                                 const unsigned short* __restrict__ wtb,
                                                 float* __restrict__ out) {
    const int bid = blockIdx.x;                 // 0..2047
    const int swz = (bid & 7) * 256 + (bid >> 3);
    const int by = swz >> 4;                    // M tile 0..127
    const int bx = swz & 15;                    // N tile 0..15
    const int i0 = by * 128;
    const int n0 = bx * 128;

    __shared__ alignas(16) unsigned short As[128 * 32];
    __shared__ alignas(16) unsigned short Bs[128 * 32];

    const int tid  = threadIdx.x;
    const int wid  = tid >> 6;
    const int lane = tid & 63;
    const int wr = wid >> 1, wc = wid & 1;
    const int lr = lane & 15, lq = lane >> 4;

    f32x4 acc[4][4];
#pragma unroll
    for (int m = 0; m < 4; ++m)
#pragma unroll
        for (int n = 0; n < 4; ++n) acc[m][n] = (f32x4){0.f, 0.f, 0.f, 0.f};

    const unsigned short* ga = adjb + (size_t)(i0 + (tid >> 2)) * V + (tid & 3) * 8;
    const unsigned short* gb = wtb  + (size_t)(n0 + (tid >> 2)) * V + (tid & 3) * 8;
    unsigned short* lA = &As[tid * 8];
    unsigned short* lB = &Bs[tid * 8];
    const size_t rowskip = (size_t)64 * V;

    for (int kt = 0; kt < 64; ++kt) {
        const int k0 = kt * 32;
        if (kt) __syncthreads();
        GLOAD_LDS16(ga + k0,           lA);
        GLOAD_LDS16(ga + rowskip + k0, lA + 256 * 8);
        GLOAD_LDS16(gb + k0,           lB);
        GLOAD_LDS16(gb + rowskip + k0, lB + 256 * 8);
        __syncthreads();

        bf16x8 a[4], b[4];
#pragma unroll
        for (int m = 0; m < 4; ++m)
            a[m] = *(const bf16x8*)&As[(wr * 64 + m * 16 + lr) * 32 + lq * 8];
#pragma unroll
        for (int n = 0; n < 4; ++n)
            b[n] = *(const bf16x8*)&Bs[(wc * 64 + n * 16 + lr) * 32 + lq * 8];
#pragma unroll
        for (int m = 0; m < 4; ++m)
#pragma unroll
            for (int n = 0; n < 4; ++n)
                acc[m][n] = __builtin_amdgcn_mfma_f32_16x16x32_bf16(a[m], b[n], acc[m][n], 0, 0, 0);
    }

    float* outp = out + (size_t)(i0 + wr * 64) * V + n0 + wc * 64;
#pragma unroll
    for (int m = 0; m < 4; ++m) {
        const int r0 = m * 16 + lq * 4;
#pragma unroll
        for (int n = 0; n < 4; ++n) {
            const int cc = n * 16 + lr;
#pragma unroll
            for (int r = 0; r < 4; ++r)
                outp[(size_t)(r0 + r) * V + cc] = acc[m][n][r];
        }
    }
}

// ============================ FALLBACK PATH (fp32, no ws) ============================

__global__ __launch_bounds__(256) void adj_kernel(const float* __restrict__ x,
                                                  float* __restrict__ adj) {
    const int n  = blockIdx.z;
    const int i0 = blockIdx.y * 64;
    const int j0 = blockIdx.x * 64;

    __shared__ float Xi[64][65];
    __shared__ float Xj[64][65];

    const float* xn = x + (size_t)n * V * C;
    const int tid = threadIdx.x;
    const int lr = tid >> 4;
    const int lc = (tid & 15) << 2;
#pragma unroll
    for (int it = 0; it < 4; ++it) {
        const int r = lr + it * 16;
        float4 vi = *(const float4*)(xn + (size_t)(i0 + r) * C + lc);
        float4 vj = *(const float4*)(xn + (size_t)(j0 + r) * C + lc);
        Xi[r][lc + 0] = vi.x; Xi[r][lc + 1] = vi.y; Xi[r][lc + 2] = vi.z; Xi[r][lc + 3] = vi.w;
        Xj[r][lc + 0] = vj.x; Xj[r][lc + 1] = vj.y; Xj[r][lc + 2] = vj.z; Xj[r][lc + 3] = vj.w;
    }
    __syncthreads();

    const int ti = (tid >> 4) << 2;
    const int tj = (tid & 15) << 2;

    float acc[4][4] = {};
#pragma unroll 4
    for (int c = 0; c < C; ++c) {
        float ai[4], bj[4];
#pragma unroll
        for (int a = 0; a < 4; ++a) ai[a] = Xi[ti + a][c];
#pragma unroll
        for (int b = 0; b < 4; ++b) bj[b] = Xj[tj + b][c];
#pragma unroll
        for (int a = 0; a < 4; ++a)
#pragma unroll
            for (int b = 0; b < 4; ++b) {
                const float d = ai[a] - bj[b];
                acc[a][b] = fmaf(d, d, acc[a][b]);
            }
    }

    float* outb = adj + ((size_t)n * V + i0) * V + j0;
#pragma unroll
    for (int a = 0; a < 4; ++a) {
        float4 o0;
        o0.x = expf(-0.5f * sqrtf(acc[a][0]));
        o0.y = expf(-0.5f * sqrtf(acc[a][1]));
        o0.z = expf(-0.5f * sqrtf(acc[a][2]));
        o0.w = expf(-0.5f * sqrtf(acc[a][3]));
        *(float4*)(outb + (size_t)(ti + a) * V + tj) = o0;
    }
}

__global__ __launch_bounds__(256) void gemm_inplace(float* __restrict__ adjout,
                                                    const float* __restrict__ w) {
    const int n  = blockIdx.y;
    const int i0 = blockIdx.x * 8;

    __shared__ float rows[8][V];

    float* base = adjout + ((size_t)n * V + i0) * V;
    const int tid = threadIdx.x;

    for (int t = tid; t < (8 * V) / 4; t += 256) {
        const int r = t >> 9;
        const int c = (t & 511) << 2;
        float4 v = *(const float4*)(base + (size_t)r * V + c);
        rows[r][c + 0] = v.x; rows[r][c + 1] = v.y; rows[r][c + 2] = v.z; rows[r][c + 3] = v.w;
    }
    __syncthreads();

    float acc[8][8] = {};
    const int k0 = tid << 3;
    const float* wp = w + k0;

    for (int j = 0; j < V; ++j) {
        float a[8];
#pragma unroll
        for (int r = 0; r < 8; ++r) a[r] = rows[r][j];
        const float* wr = wp + (size_t)j * V;
        const float4 w0 = *(const float4*)(wr);
        const float4 w1 = *(const float4*)(wr + 4);
        const float wv[8] = {w0.x, w0.y, w0.z, w0.w, w1.x, w1.y, w1.z, w1.w};
#pragma unroll
        for (int r = 0; r < 8; ++r)
#pragma unroll
            for (int c = 0; c < 8; ++c)
                acc[r][c] = fmaf(a[r], wv[c], acc[r][c]);
    }

#pragma unroll
    for (int r = 0; r < 8; ++r) {
        float4 o0, o1;
        o0.x = acc[r][0]; o0.y = acc[r][1]; o0.z = acc[r][2]; o0.w = acc[r][3];
        o1.x = acc[r][4]; o1.y = acc[r][5]; o1.z = acc[r][6]; o1.w = acc[r][7];
        *(float4*)(base + (size_t)r * V + k0)     = o0;
        *(float4*)(base + (size_t)r * V + k0 + 4) = o1;
    }
}

// ---------------- in-place row softmax (shared by both paths) ----------------
__global__ __launch_bounds__(256) void softmax_kernel(float* __restrict__ out) {
    const int row  = blockIdx.x * 4 + (threadIdx.x >> 6);
    const int lane = threadIdx.x & 63;
    float* p = out + (size_t)row * V;

    float4 v[8];
#pragma unroll
    for (int s = 0; s < 8; ++s)
        v[s] = *(const float4*)(p + (size_t)(s * 64 + lane) * 4);

    float m = -INFINITY;
#pragma unroll
    for (int s = 0; s < 8; ++s)
        m = fmaxf(m, fmaxf(fmaxf(v[s].x, v[s].y), fmaxf(v[s].z, v[s].w)));
#pragma unroll
    for (int o = 32; o; o >>= 1) m = fmaxf(m, __shfl_xor(m, o));

    float sum = 0.0f;
#pragma unroll
    for (int s = 0; s < 8; ++s) {
        v[s].x = expf(v[s].x - m);
        v[s].y = expf(v[s].y - m);
        v[s].z = expf(v[s].z - m);
        v[s].w = expf(v[s].w - m);
        sum += (v[s].x + v[s].y) + (v[s].z + v[s].w);
    }
#pragma unroll
    for (int o = 32; o; o >>= 1) sum += __shfl_xor(sum, o);

    const float inv = 1.0f / sum;
#pragma unroll
    for (int s = 0; s < 8; ++s) {
        float4 o4;
        o4.x = v[s].x * inv; o4.y = v[s].y * inv;
        o4.z = v[s].z * inv; o4.w = v[s].w * inv;
        *(float4*)(p + (size_t)(s * 64 + lane) * 4) = o4;
    }
}

extern "C" void kernel_launch(void* const* d_in, const int* in_sizes, int n_in,
                              void* d_out, int out_size, void* d_ws, size_t ws_size,
                              hipStream_t stream) {
    const float* x = (const float*)d_in[0];
    const float* w = (const float*)d_in[1];
    float* out = (float*)d_out;

    const size_t adj_elems = (size_t)M_TOTAL * V;
    const size_t need = adj_elems * 2 + (size_t)V * V * 2;          // 75,497,472 B

    if (ws_size >= need) {
        unsigned short* adjb = (unsigned short*)d_ws;
        unsigned short* wtb  = adjb + adj_elems;
        float* q = out;   // q[16384] parked at start of d_out; GEMM overwrites later

        q_kernel<<<M_TOTAL / 64, 256, 0, stream>>>(x, q);
        adj_mfma<<<dim3(V / 128, V / 128, NB), 256, 0, stream>>>(x, q, adjb);
        wt_kernel<<<dim3(V / 64, V / 64), 256, 0, stream>>>(w, wtb);
        gemm_mfma<<<2048, 256, 0, stream>>>(adjb, wtb, out);
        softmax_kernel<<<(NB * V) / 4, 256, 0, stream>>>(out);
    } else {
        dim3 g1(V / 64, V / 64, NB);
        adj_kernel<<<g1, 256, 0, stream>>>(x, out);
        dim3 g2(V / 8, NB);
        gemm_inplace<<<g2, 256, 0, stream>>>(out, w);
        softmax_kernel<<<(NB * V) / 4, 256, 0, stream>>>(out);
    }
}

// Round 4
// 208.029 us; speedup vs baseline: 9.0945x; 1.1718x over previous
//
#include <hip/hip_runtime.h>
#include <hip/hip_bf16.h>
#include <math.h>

#define V 2048
#define C 64
#define NB 8
#define M_TOTAL (NB * V)   // 16384 rows total

typedef __attribute__((ext_vector_type(8))) short bf16x8;
typedef __attribute__((ext_vector_type(4))) float f32x4;

static __device__ __forceinline__ unsigned short f2bf(float f) {
    __hip_bfloat16 h = __float2bfloat16(f);   // RNE
    return *reinterpret_cast<unsigned short*>(&h);
}

#define GLOAD_LDS16(g, l)                                                        \
    __builtin_amdgcn_global_load_lds((const __attribute__((address_space(1))) void*)(g), \
                                     (__attribute__((address_space(3))) void*)(l), 16, 0, 0)

// ============================ FAST PATH (needs d_ws) ============================

// ---- q_kernel: q[row] = MFMA-diagonal of bf16(x_row) . bf16(x_row) ----
// Same MFMA chain as adj_mfma so q[i] bit-equals G_ii => diagonal d^2 == 0.
__global__ __launch_bounds__(256) void q_kernel(const float* __restrict__ x,
                                                float* __restrict__ q) {
    const int gw   = blockIdx.x * 4 + (threadIdx.x >> 6);
    const int lane = threadIdx.x & 63;
    const int lr = lane & 15, lq = lane >> 4;

    const float* rp = x + (size_t)(gw * 16 + lr) * C + lq * 8;
    float4 f0 = *(const float4*)(rp);
    float4 f1 = *(const float4*)(rp + 4);
    float4 f2 = *(const float4*)(rp + 32);
    float4 f3 = *(const float4*)(rp + 36);

    bf16x8 a0, a1;
    a0[0] = (short)f2bf(f0.x); a0[1] = (short)f2bf(f0.y);
    a0[2] = (short)f2bf(f0.z); a0[3] = (short)f2bf(f0.w);
    a0[4] = (short)f2bf(f1.x); a0[5] = (short)f2bf(f1.y);
    a0[6] = (short)f2bf(f1.z); a0[7] = (short)f2bf(f1.w);
    a1[0] = (short)f2bf(f2.x); a1[1] = (short)f2bf(f2.y);
    a1[2] = (short)f2bf(f2.z); a1[3] = (short)f2bf(f2.w);
    a1[4] = (short)f2bf(f3.x); a1[5] = (short)f2bf(f3.y);
    a1[6] = (short)f2bf(f3.z); a1[7] = (short)f2bf(f3.w);

    f32x4 acc = (f32x4){0.f, 0.f, 0.f, 0.f};
    acc = __builtin_amdgcn_mfma_f32_16x16x32_bf16(a0, a0, acc, 0, 0, 0);
    acc = __builtin_amdgcn_mfma_f32_16x16x32_bf16(a1, a1, acc, 0, 0, 0);

    const int r = lr;
    if (lq == (r >> 2)) q[gw * 16 + r] = acc[r & 3];
}

// ---- adj via MFMA gram ----
__global__ __launch_bounds__(256) void adj_mfma(const float* __restrict__ x,
                                                const float* __restrict__ q,
                                                unsigned short* __restrict__ adjb) {
    const int n  = blockIdx.z;
    const int i0 = blockIdx.y * 128;
    const int j0 = blockIdx.x * 128;
    const size_t nV = (size_t)n * V;

    __shared__ short Xi[128][72];
    __shared__ short Xj[128][72];
    __shared__ float Qi[128];
    __shared__ float Qj[128];

    const float* xn = x + nV * C;
    const int tid = threadIdx.x;

    for (int idx = tid; idx < 1024; idx += 256) {
        const int row = idx >> 3;
        const int c8  = (idx & 7) * 8;
        float4 ai0 = *(const float4*)(xn + (size_t)(i0 + row) * C + c8);
        float4 ai1 = *(const float4*)(xn + (size_t)(i0 + row) * C + c8 + 4);
        float4 aj0 = *(const float4*)(xn + (size_t)(j0 + row) * C + c8);
        float4 aj1 = *(const float4*)(xn + (size_t)(j0 + row) * C + c8 + 4);
        bf16x8 pi, pj;
        pi[0] = (short)f2bf(ai0.x); pi[1] = (short)f2bf(ai0.y);
        pi[2] = (short)f2bf(ai0.z); pi[3] = (short)f2bf(ai0.w);
        pi[4] = (short)f2bf(ai1.x); pi[5] = (short)f2bf(ai1.y);
        pi[6] = (short)f2bf(ai1.z); pi[7] = (short)f2bf(ai1.w);
        pj[0] = (short)f2bf(aj0.x); pj[1] = (short)f2bf(aj0.y);
        pj[2] = (short)f2bf(aj0.z); pj[3] = (short)f2bf(aj0.w);
        pj[4] = (short)f2bf(aj1.x); pj[5] = (short)f2bf(aj1.y);
        pj[6] = (short)f2bf(aj1.z); pj[7] = (short)f2bf(aj1.w);
        *(bf16x8*)&Xi[row][c8] = pi;
        *(bf16x8*)&Xj[row][c8] = pj;
    }
    if (tid < 128)       Qi[tid]        = q[nV + i0 + tid];
    else                 Qj[tid - 128]  = q[nV + j0 + (tid - 128)];
    __syncthreads();

    const int wid  = tid >> 6;
    const int lane = tid & 63;
    const int wr = wid >> 1, wc = wid & 1;
    const int lr = lane & 15, lq = lane >> 4;

    bf16x8 a[4][2], b[4][2];
#pragma unroll
    for (int m = 0; m < 4; ++m) {
        a[m][0] = *(const bf16x8*)&Xi[wr * 64 + m * 16 + lr][lq * 8];
        a[m][1] = *(const bf16x8*)&Xi[wr * 64 + m * 16 + lr][32 + lq * 8];
    }
#pragma unroll
    for (int nn = 0; nn < 4; ++nn) {
        b[nn][0] = *(const bf16x8*)&Xj[wc * 64 + nn * 16 + lr][lq * 8];
        b[nn][1] = *(const bf16x8*)&Xj[wc * 64 + nn * 16 + lr][32 + lq * 8];
    }

#pragma unroll
    for (int m = 0; m < 4; ++m) {
#pragma unroll
        for (int nn = 0; nn < 4; ++nn) {
            f32x4 g = (f32x4){0.f, 0.f, 0.f, 0.f};
            g = __builtin_amdgcn_mfma_f32_16x16x32_bf16(a[m][0], b[nn][0], g, 0, 0, 0);
            g = __builtin_amdgcn_mfma_f32_16x16x32_bf16(a[m][1], b[nn][1], g, 0, 0, 0);
            const int col_l = wc * 64 + nn * 16 + lr;
            const float qj = Qj[col_l];
#pragma unroll
            for (int r = 0; r < 4; ++r) {
                const int row_l = wr * 64 + m * 16 + lq * 4 + r;
                float d2 = Qi[row_l] + qj - 2.0f * g[r];
                d2 = fmaxf(d2, 0.0f);
                const float e = expf(-0.5f * sqrtf(d2));
                adjb[(nV + i0 + row_l) * V + j0 + col_l] = f2bf(e);
            }
        }
    }
}

// ---- W transpose to bf16 ----
__global__ __launch_bounds__(256) void wt_kernel(const float* __restrict__ w,
                                                 unsigned short* __restrict__ wt) {
    __shared__ float tile[64][65];
    const int r0 = blockIdx.y * 64, c0 = blockIdx.x * 64;
    const int tr = threadIdx.x >> 4;
    const int tc4 = (threadIdx.x & 15) << 2;
#pragma unroll
    for (int it = 0; it < 4; ++it) {
        const int r = tr + 16 * it;
        float4 v = *(const float4*)(w + (size_t)(r0 + r) * V + c0 + tc4);
        tile[r][tc4 + 0] = v.x; tile[r][tc4 + 1] = v.y;
        tile[r][tc4 + 2] = v.z; tile[r][tc4 + 3] = v.w;
    }
    __syncthreads();
#pragma unroll
    for (int it = 0; it < 4; ++it) {
        const int cr = tr + 16 * it;
        ushort4 o;
        o.x = f2bf(tile[tc4 + 0][cr]);
        o.y = f2bf(tile[tc4 + 1][cr]);
        o.z = f2bf(tile[tc4 + 2][cr]);
        o.w = f2bf(tile[tc4 + 3][cr]);
        *(ushort4*)(wt + (size_t)(c0 + cr) * V + r0 + tc4) = o;
    }
}

// ============== 256x256 8-phase MFMA GEMM (T2+T3+T4+T5 template) ==============
// BM=BN=256, BK=64, 8 waves (2Mx4N), 128 KiB dynamic LDS (2 bufs).
// LDS regions per buf (16 KiB each, contiguous): Ak0 | Ak1 | Bk0 | Bk1
//   (k-split: Akx = 256 rows x 32 k of bf16). Layout [row][32k], 64 B rows,
//   XOR swizzle: byte_in_row ^= ((row>>1)&3)<<4  -> 16 rows spread over 8
//   bank-quads (2-way, free). Applied on BOTH sides: pre-swizzled global
//   source for global_load_lds (linear LDS dest) + swizzled ds_read address.
// Staging slot = region's last-read phase + 1:
//   ph1: buf1.Ak1<-t(2i+1)   ph2: buf0.Bk0<-t(2i+2)  ph3: buf0.Ak0  ph4: buf0.Bk1
//   ph5: buf0.Ak1            ph6: buf1.Bk0<-t(2i+3)  ph7: buf1.Ak0  ph8: buf1.Bk1
// vmcnt(6) at ph4/ph8 (after that phase's issue) == "all but last 3 phases'
// loads landed" -> exactly covers the buffer read in the next 4 phases.
__device__ __forceinline__ void stage_region(char* smem, int regionOff,
                                             const unsigned short* gbase,
                                             int tile, int ks, int tid) {
#pragma unroll
    for (int s = 0; s < 2; ++s) {
        const int off = s * 8192 + tid * 16;       // linear LDS byte offset
        const int row = off >> 6;
        const int pb  = off & 63;
        const int lb  = pb ^ (((row >> 1) & 3) << 4);  // inverse swizzle on source
        const unsigned short* g = gbase + (size_t)row * V + tile * 64 + ks * 32 + (lb >> 1);
        GLOAD_LDS16(g, smem + regionOff + off);
    }
}

#define LDS_FRAG(BUF, BOFF, KS, ROW)                                             \
    (*(const bf16x8*)(smem + (BUF) * 65536 + (BOFF) + (KS) * 16384 +             \
                      (ROW) * 64 + (lqb ^ ((((ROW) >> 1) & 3) << 4))))

#define PHASE(BUF, MS, KS, LOADB, STAGE_STMT, WAITV)                             \
    {                                                                            \
        bf16x8 af[4];                                                            \
        _Pragma("unroll") for (int m = 0; m < 4; ++m) {                          \
            const int row = wr128 + ((MS) + m) * 16 + lr;                        \
            af[m] = LDS_FRAG(BUF, 0, KS, row);                                   \
        }                                                                        \
        if (LOADB) {                                                             \
            _Pragma("unroll") for (int n = 0; n < 4; ++n) {                      \
                const int row = wc64 + n * 16 + lr;                              \
                bf[n] = LDS_FRAG(BUF, 32768, KS, row);                           \
            }                                                                    \
        }                                                                        \
        STAGE_STMT;                                                              \
        if (WAITV) {                                                             \
            asm volatile("s_waitcnt vmcnt(6)" ::: "memory");                     \
            __builtin_amdgcn_sched_barrier(0);                                   \
        }                                                                        \
        __builtin_amdgcn_s_barrier();                                            \
        asm volatile("s_waitcnt lgkmcnt(0)" ::: "memory");                       \
        __builtin_amdgcn_sched_barrier(0);                                       \
        __builtin_amdgcn_s_setprio(1);                                           \
        _Pragma("unroll") for (int m = 0; m < 4; ++m)                            \
            _Pragma("unroll") for (int n = 0; n < 4; ++n)                        \
                acc[(MS) + m][n] = __builtin_amdgcn_mfma_f32_16x16x32_bf16(      \
                    af[m], bf[n], acc[(MS) + m][n], 0, 0, 0);                    \
        __builtin_amdgcn_s_setprio(0);                                           \
        __builtin_amdgcn_s_barrier();                                            \
    }

__global__ __launch_bounds__(512, 2) void gemm_8ph(const unsigned short* __restrict__ adjb,
                                                   const unsigned short* __restrict__ wtb,
                                                   float* __restrict__ out) {
    extern __shared__ char smem[];

    // grid = 512 = 64 Mtiles x 8 Ntiles; bijective XCD swizzle (512 % 8 == 0)
    const int bid = blockIdx.x;
    const int swz = (bid & 7) * 64 + (bid >> 3);
    const int by = swz >> 3;            // 0..63
    const int bx = swz & 7;             // 0..7
    const int i0 = by * 256;
    const int n0 = bx * 256;

    const int tid  = threadIdx.x;
    const int wid  = tid >> 6;
    const int lane = tid & 63;
    const int wr = wid >> 2, wc = wid & 3;        // 2 x 4 waves
    const int wr128 = wr * 128, wc64 = wc * 64;
    const int lr = lane & 15, lq = lane >> 4;
    const int lqb = lq * 16;

    const unsigned short* gA = adjb + (size_t)i0 * V;
    const unsigned short* gB = wtb  + (size_t)n0 * V;

    f32x4 acc[8][4];
#pragma unroll
    for (int m = 0; m < 8; ++m)
#pragma unroll
        for (int n = 0; n < 4; ++n) acc[m][n] = (f32x4){0.f, 0.f, 0.f, 0.f};

    // ---- prologue: buf0 <- tile0 (4 regions), buf1 <- tile1 (Bk0,Ak0,Bk1) ----
    stage_region(smem, 32768,         gB, 0, 0, tid);  // buf0.Bk0
    stage_region(smem, 0,             gA, 0, 0, tid);  // buf0.Ak0
    stage_region(smem, 49152,         gB, 0, 1, tid);  // buf0.Bk1
    stage_region(smem, 16384,         gA, 0, 1, tid);  // buf0.Ak1
    stage_region(smem, 65536 + 32768, gB, 1, 0, tid);  // buf1.Bk0
    stage_region(smem, 65536 + 0,     gA, 1, 0, tid);  // buf1.Ak0
    stage_region(smem, 65536 + 49152, gB, 1, 1, tid);  // buf1.Bk1
    asm volatile("s_waitcnt vmcnt(6)" ::: "memory");   // buf0's 8 loads landed
    __builtin_amdgcn_sched_barrier(0);
    __builtin_amdgcn_s_barrier();

    bf16x8 bf[4];

#pragma unroll 1
    for (int i = 0; i < 16; ++i) {
        const int t1b = 2 * i + 1;                      // buf1.Ak1's tile
        const int t2  = (2 * i + 2 < 32) ? 2 * i + 2 : 31;   // clamp: idempotent tail
        const int t3  = (2 * i + 3 < 32) ? 2 * i + 3 : 31;

        PHASE(0, 0, 0, true,  stage_region(smem, 65536 + 16384, gA, t1b, 1, tid), false)
        PHASE(0, 4, 0, false, stage_region(smem, 32768,         gB, t2,  0, tid), false)
        PHASE(0, 0, 1, true,  stage_region(smem, 0,             gA, t2,  0, tid), false)
        PHASE(0, 4, 1, false, stage_region(smem, 49152,         gB, t2,  1, tid), true)
        PHASE(1, 0, 0, true,  stage_region(smem, 16384,         gA, t2,  1, tid), false)
        PHASE(1, 4, 0, false, stage_region(smem, 65536 + 32768, gB, t3,  0, tid), false)
        PHASE(1, 0, 1, true,  stage_region(smem, 65536 + 0,     gA, t3,  0, tid), false)
        PHASE(1, 4, 1, false, stage_region(smem, 65536 + 49152, gB, t3,  1, tid), true)
    }

    // ---- C write: row = m*16 + lq*4 + r, col = n*16 + lr within wave tile ----
    float* op = out + (size_t)(i0 + wr128) * V + n0 + wc64;
#pragma unroll
    for (int m = 0; m < 8; ++m)
#pragma unroll
        for (int n = 0; n < 4; ++n)
#pragma unroll
            for (int r = 0; r < 4; ++r)
                op[(size_t)(m * 16 + lq * 4 + r) * V + n * 16 + lr] = acc[m][n][r];
}

// ---- backup MFMA GEMM (proven round-3 kernel), used if LDS attribute fails ----
__global__ __launch_bounds__(256) void gemm_mfma(const unsigned short* __restrict__ adjb,
                                                 const unsigned short* __restrict__ wtb,
                                                 float* __restrict__ out) {
    const int bid = blockIdx.x;
    const int swz = (bid & 7) * 256 + (bid >> 3);
    const int by = swz >> 4;
    const int bx = swz & 15;
    const int i0 = by * 128;
    const int n0 = bx * 128;

    __shared__ alignas(16) unsigned short As[128 * 32];
    __shared__ alignas(16) unsigned short Bs[128 * 32];

    const int tid  = threadIdx.x;
    const int wid  = tid >> 6;
    const int lane = tid & 63;
    const int wr = wid >> 1, wc = wid & 1;
    const int lr = lane & 15, lq = lane >> 4;

    f32x4 acc[4][4];
#pragma unroll
    for (int m = 0; m < 4; ++m)
#pragma unroll
        for (int n = 0; n < 4; ++n) acc[m][n] = (f32x4){0.f, 0.f, 0.f, 0.f};

    const unsigned short* ga = adjb + (size_t)(i0 + (tid >> 2)) * V + (tid & 3) * 8;
    const unsigned short* gb = wtb  + (size_t)(n0 + (tid >> 2)) * V + (tid & 3) * 8;
    unsigned short* lA = &As[tid * 8];
    unsigned short* lB = &Bs[tid * 8];
    const size_t rowskip = (size_t)64 * V;

    for (int kt = 0; kt < 64; ++kt) {
        const int k0 = kt * 32;
        if (kt) __syncthreads();
        GLOAD_LDS16(ga + k0,           lA);
        GLOAD_LDS16(ga + rowskip + k0, lA + 256 * 8);
        GLOAD_LDS16(gb + k0,           lB);
        GLOAD_LDS16(gb + rowskip + k0, lB + 256 * 8);
        __syncthreads();

        bf16x8 a[4], b[4];
#pragma unroll
        for (int m = 0; m < 4; ++m)
            a[m] = *(const bf16x8*)&As[(wr * 64 + m * 16 + lr) * 32 + lq * 8];
#pragma unroll
        for (int n = 0; n < 4; ++n)
            b[n] = *(const bf16x8*)&Bs[(wc * 64 + n * 16 + lr) * 32 + lq * 8];
#pragma unroll
        for (int m = 0; m < 4; ++m)
#pragma unroll
            for (int n = 0; n < 4; ++n)
                acc[m][n] = __builtin_amdgcn_mfma_f32_16x16x32_bf16(a[m], b[n], acc[m][n], 0, 0, 0);
    }

    float* outp = out + (size_t)(i0 + wr * 64) * V + n0 + wc * 64;
#pragma unroll
    for (int m = 0; m < 4; ++m) {
        const int r0 = m * 16 + lq * 4;
#pragma unroll
        for (int n = 0; n < 4; ++n) {
            const int cc = n * 16 + lr;
#pragma unroll
            for (int r = 0; r < 4; ++r)
                outp[(size_t)(r0 + r) * V + cc] = acc[m][n][r];
        }
    }
}

// ============================ FALLBACK PATH (fp32, no ws) ============================

__global__ __launch_bounds__(256) void adj_kernel(const float* __restrict__ x,
                                                  float* __restrict__ adj) {
    const int n  = blockIdx.z;
    const int i0 = blockIdx.y * 64;
    const int j0 = blockIdx.x * 64;

    __shared__ float Xi[64][65];
    __shared__ float Xj[64][65];

    const float* xn = x + (size_t)n * V * C;
    const int tid = threadIdx.x;
    const int lr = tid >> 4;
    const int lc = (tid & 15) << 2;
#pragma unroll
    for (int it = 0; it < 4; ++it) {
        const int r = lr + it * 16;
        float4 vi = *(const float4*)(xn + (size_t)(i0 + r) * C + lc);
        float4 vj = *(const float4*)(xn + (size_t)(j0 + r) * C + lc);
        Xi[r][lc + 0] = vi.x; Xi[r][lc + 1] = vi.y; Xi[r][lc + 2] = vi.z; Xi[r][lc + 3] = vi.w;
        Xj[r][lc + 0] = vj.x; Xj[r][lc + 1] = vj.y; Xj[r][lc + 2] = vj.z; Xj[r][lc + 3] = vj.w;
    }
    __syncthreads();

    const int ti = (tid >> 4) << 2;
    const int tj = (tid & 15) << 2;

    float acc[4][4] = {};
#pragma unroll 4
    for (int c = 0; c < C; ++c) {
        float ai[4], bj[4];
#pragma unroll
        for (int a = 0; a < 4; ++a) ai[a] = Xi[ti + a][c];
#pragma unroll
        for (int b = 0; b < 4; ++b) bj[b] = Xj[tj + b][c];
#pragma unroll
        for (int a = 0; a < 4; ++a)
#pragma unroll
            for (int b = 0; b < 4; ++b) {
                const float d = ai[a] - bj[b];
                acc[a][b] = fmaf(d, d, acc[a][b]);
            }
    }

    float* outb = adj + ((size_t)n * V + i0) * V + j0;
#pragma unroll
    for (int a = 0; a < 4; ++a) {
        float4 o0;
        o0.x = expf(-0.5f * sqrtf(acc[a][0]));
        o0.y = expf(-0.5f * sqrtf(acc[a][1]));
        o0.z = expf(-0.5f * sqrtf(acc[a][2]));
        o0.w = expf(-0.5f * sqrtf(acc[a][3]));
        *(float4*)(outb + (size_t)(ti + a) * V + tj) = o0;
    }
}

__global__ __launch_bounds__(256) void gemm_inplace(float* __restrict__ adjout,
                                                    const float* __restrict__ w) {
    const int n  = blockIdx.y;
    const int i0 = blockIdx.x * 8;

    __shared__ float rows[8][V];

    float* base = adjout + ((size_t)n * V + i0) * V;
    const int tid = threadIdx.x;

    for (int t = tid; t < (8 * V) / 4; t += 256) {
        const int r = t >> 9;
        const int c = (t & 511) << 2;
        float4 v = *(const float4*)(base + (size_t)r * V + c);
        rows[r][c + 0] = v.x; rows[r][c + 1] = v.y; rows[r][c + 2] = v.z; rows[r][c + 3] = v.w;
    }
    __syncthreads();

    float acc[8][8] = {};
    const int k0 = tid << 3;
    const float* wp = w + k0;

    for (int j = 0; j < V; ++j) {
        float a[8];
#pragma unroll
        for (int r = 0; r < 8; ++r) a[r] = rows[r][j];
        const float* wr = wp + (size_t)j * V;
        const float4 w0 = *(const float4*)(wr);
        const float4 w1 = *(const float4*)(wr + 4);
        const float wv[8] = {w0.x, w0.y, w0.z, w0.w, w1.x, w1.y, w1.z, w1.w};
#pragma unroll
        for (int r = 0; r < 8; ++r)
#pragma unroll
            for (int c = 0; c < 8; ++c)
                acc[r][c] = fmaf(a[r], wv[c], acc[r][c]);
    }

#pragma unroll
    for (int r = 0; r < 8; ++r) {
        float4 o0, o1;
        o0.x = acc[r][0]; o0.y = acc[r][1]; o0.z = acc[r][2]; o0.w = acc[r][3];
        o1.x = acc[r][4]; o1.y = acc[r][5]; o1.z = acc[r][6]; o1.w = acc[r][7];
        *(float4*)(base + (size_t)r * V + k0)     = o0;
        *(float4*)(base + (size_t)r * V + k0 + 4) = o1;
    }
}

// ---------------- in-place row softmax (shared by both paths) ----------------
__global__ __launch_bounds__(256) void softmax_kernel(float* __restrict__ out) {
    const int row  = blockIdx.x * 4 + (threadIdx.x >> 6);
    const int lane = threadIdx.x & 63;
    float* p = out + (size_t)row * V;

    float4 v[8];
#pragma unroll
    for (int s = 0; s < 8; ++s)
        v[s] = *(const float4*)(p + (size_t)(s * 64 + lane) * 4);

    float m = -INFINITY;
#pragma unroll
    for (int s = 0; s < 8; ++s)
        m = fmaxf(m, fmaxf(fmaxf(v[s].x, v[s].y), fmaxf(v[s].z, v[s].w)));
#pragma unroll
    for (int o = 32; o; o >>= 1) m = fmaxf(m, __shfl_xor(m, o));

    float sum = 0.0f;
#pragma unroll
    for (int s = 0; s < 8; ++s) {
        v[s].x = expf(v[s].x - m);
        v[s].y = expf(v[s].y - m);
        v[s].z = expf(v[s].z - m);
        v[s].w = expf(v[s].w - m);
        sum += (v[s].x + v[s].y) + (v[s].z + v[s].w);
    }
#pragma unroll
    for (int o = 32; o; o >>= 1) sum += __shfl_xor(sum, o);

    const float inv = 1.0f / sum;
#pragma unroll
    for (int s = 0; s < 8; ++s) {
        float4 o4;
        o4.x = v[s].x * inv; o4.y = v[s].y * inv;
        o4.z = v[s].z * inv; o4.w = v[s].w * inv;
        *(float4*)(p + (size_t)(s * 64 + lane) * 4) = o4;
    }
}

extern "C" void kernel_launch(void* const* d_in, const int* in_sizes, int n_in,
                              void* d_out, int out_size, void* d_ws, size_t ws_size,
                              hipStream_t stream) {
    const float* x = (const float*)d_in[0];
    const float* w = (const float*)d_in[1];
    float* out = (float*)d_out;

    const size_t adj_elems = (size_t)M_TOTAL * V;
    const size_t need = adj_elems * 2 + (size_t)V * V * 2;          // 75,497,472 B

    if (ws_size >= need) {
        unsigned short* adjb = (unsigned short*)d_ws;
        unsigned short* wtb  = adjb + adj_elems;
        float* q = out;   // parked at start of d_out; GEMM overwrites later

        q_kernel<<<M_TOTAL / 64, 256, 0, stream>>>(x, q);
        adj_mfma<<<dim3(V / 128, V / 128, NB), 256, 0, stream>>>(x, q, adjb);
        wt_kernel<<<dim3(V / 64, V / 64), 256, 0, stream>>>(w, wtb);

        hipError_t attr_ok = hipFuncSetAttribute(
            reinterpret_cast<const void*>(&gemm_8ph),
            hipFuncAttributeMaxDynamicSharedMemorySize, 131072);
        if (attr_ok == hipSuccess) {
            gemm_8ph<<<512, 512, 131072, stream>>>(adjb, wtb, out);
        } else {
            gemm_mfma<<<2048, 256, 0, stream>>>(adjb, wtb, out);
        }
        softmax_kernel<<<(NB * V) / 4, 256, 0, stream>>>(out);
    } else {
        dim3 g1(V / 64, V / 64, NB);
        adj_kernel<<<g1, 256, 0, stream>>>(x, out);
        dim3 g2(V / 8, NB);
        gemm_inplace<<<g2, 256, 0, stream>>>(out, w);
        softmax_kernel<<<(NB * V) / 4, 256, 0, stream>>>(out);
    }
}